// Round 8
// baseline (379.410 us; speedup 1.0000x reference)
//
#include <hip/hip_runtime.h>
#include <math.h>

constexpr int N = 100000;
constexpr int E = 1600000;
constexpr int C = 128;
constexpr int NPB   = 256;                       // nodes per bucket (pow2 -> shifts)
constexpr int NBUCK = (N + NPB - 1) / NPB;       // 391 buckets
constexpr int CAP   = 9472;                      // staging cap/bucket (mean 8192, +14 sigma)
constexpr int ADJ_STRIDE = CAP + NPB * 7;        // 11264: padded adj slots per bucket
constexpr int GPAD = 16;                         // gcount stride: 1 counter per 64B line

typedef __attribute__((ext_vector_type(8))) short bf16x8;
typedef __attribute__((ext_vector_type(4))) float f32x4;

__device__ inline unsigned f2bf(float f) {   // fp32 -> bf16 bits, RNE
    unsigned u = __float_as_uint(f);
    return (u + 0x7fffu + ((u >> 16) & 1u)) >> 16;
}
__device__ inline unsigned pack2(float lo, float hi) {
    return f2bf(lo) | (f2bf(hi) << 16);
}
__device__ inline float bf_lo(unsigned m) { return __uint_as_float(m << 16); }
__device__ inline float bf_hi(unsigned m) { return __uint_as_float(m & 0xffff0000u); }

// ------------------------------------------------------------- bin pass ----
// count -> reserve -> re-read+scatter; line-padded global counters (round-7
// fix, confirmed: k_bin fell out of the top-5). Blocks 0..63 also split W
// into fragment-linear bf16 hi/lo; block 0 zeroes dummy z-row N.
__global__ __launch_bounds__(256) void k_bin(const int* __restrict__ ei,
                                             int* __restrict__ gcount,
                                             unsigned* __restrict__ staging,
                                             const float* __restrict__ W,
                                             unsigned short* __restrict__ wfrag,
                                             unsigned* __restrict__ z16) {
    const int t = threadIdx.x;
    if (blockIdx.x < 64) {
        const int i = blockIdx.x * 256 + t;      // i < 16384 = C*C
        const int k = i >> 7, c = i & 127;
        const int ct = c >> 4, lr = c & 15;
        const int kc = k >> 5, lg = (k >> 3) & 3, e = k & 7;
        const int idx = ((ct * 4 + kc) * 64 + lg * 16 + lr) * 8 + e;
        const float f = W[i];
        const unsigned hb = f2bf(f);
        wfrag[idx]         = (unsigned short)hb;
        wfrag[16384 + idx] = (unsigned short)f2bf(f - __uint_as_float(hb << 16));
        if (blockIdx.x == 0 && t < 64) z16[(size_t)N * 64 + t] = 0u;
    }
    __shared__ int cnt[NBUCK];
    const long tile = (long)blockIdx.x * 4096;
    for (int i = t; i < NBUCK; i += 256) cnt[i] = 0;
    __syncthreads();
    // phase 1: count
#pragma unroll
    for (int j = 0; j < 16; ++j) {
        const long e = tile + j * 256 + t;
        if (e < E) {
            const int u = ei[e];
            const int v = ei[E + e];
            atomicAdd(&cnt[u >> 8], 1);
            atomicAdd(&cnt[v >> 8], 1);
        }
    }
    __syncthreads();
    // reserve: one padded global atomic per bucket; fold base into cnt
    for (int i = t; i < NBUCK; i += 256) {
        const int c = cnt[i];
        cnt[i] = atomicAdd(&gcount[i * GPAD], c);
    }
    __syncthreads();
    // phase 2: re-read (L2-warm) -> absolute position -> scatter
#pragma unroll
    for (int j = 0; j < 16; ++j) {
        const long e = tile + j * 256 + t;
        if (e < E) {
            const int u = ei[e];
            const int v = ei[E + e];
            const int bu = u >> 8, bv = v >> 8;
            const int pu = atomicAdd(&cnt[bu], 1);
            const int pv = atomicAdd(&cnt[bv], 1);
            staging[(size_t)bu * CAP + pu] = ((unsigned)(u & 255) << 17) | (unsigned)v;
            staging[(size_t)bv * CAP + pv] = ((unsigned)(v & 255) << 17) | (unsigned)u;
        }
    }
}

// -------------------------------------------------- per-bucket CSR build ---
__global__ __launch_bounds__(512) void k_csr(const unsigned* __restrict__ staging,
                                             const int* __restrict__ gcount,
                                             int* __restrict__ deg,
                                             float* __restrict__ dinv,
                                             int* __restrict__ rowptr,
                                             int* __restrict__ adj) {
    __shared__ int hist[NPB];
    __shared__ int wpart[4];
    const int g = blockIdx.x;
    const int t = threadIdx.x;
    const int lane = t & 63, wid = t >> 6;
    const int cnt = gcount[g * GPAD];
    int* slice = adj + (size_t)g * ADJ_STRIDE;
    for (int i = t; i < NPB; i += 512) hist[i] = 0;
    __syncthreads();
    const unsigned* base = staging + (size_t)g * CAP;
    for (int i = t; i < cnt; i += 512) atomicAdd(&hist[base[i] >> 17], 1);
    __syncthreads();
    const int d  = (t < NPB) ? hist[t] : 0;
    const int pd = (d + 7) & ~7;
    int v = pd;
#pragma unroll
    for (int off = 1; off < 64; off <<= 1) {
        int n = __shfl_up(v, off);
        if (lane >= off) v += n;
    }
    if (lane == 63 && wid < 4) wpart[wid] = v;
    __syncthreads();
    if (t == 0) {
        int r = 0;
#pragma unroll
        for (int w = 0; w < 4; ++w) { int x = wpart[w]; wpart[w] = r; r += x; }
    }
    __syncthreads();
    const int pstart = v - pd + ((wid < 4) ? wpart[wid] : 0);
    if (t < NPB) {
        const int node = g * NPB + t;
        if (node < N) {
            deg[node]    = d;
            dinv[node]   = rsqrtf((float)d + 1.0f);
            rowptr[node] = g * ADJ_STRIDE + pstart;
        }
        for (int i = d; i < pd; ++i) slice[pstart + i] = N;   // precise pad fill
    }
    __syncthreads();
    if (t < NPB) hist[t] = pstart;   // cursor for pass 2
    __syncthreads();
    for (int i = t; i < cnt; i += 512) {
        const unsigned e = base[i];
        const int pos = atomicAdd(&hist[e >> 17], 1);
        slice[pos] = (int)(e & 0x1ffffu);
    }
}

// ------------------------------------------------------------------ GEMM ---
// z16 = bf16(dinv * (x @ W)) via split-bf16 MFMA.
// Round-8 restructure for occupancy (round 7: 49us with 8.5% occupancy,
// all pipes <11% -- latency-gapped at 2 waves/SIMD):
//  - 512-thread blocks (8 waves) share the 64 KB W-LDS -> 2 blocks/CU =
//    16 waves/CU (2x the old ceiling).
//  - __launch_bounds__(512,4) caps VGPR at 128 so 4 waves/SIMD fit; the
//    ct-pair-outer loop keeps only 2 accumulators + 4 W fragments live
//    (x converted once into bh/bl[4], 32 VGPR).
__global__ __launch_bounds__(512, 4) void k_gemm(const float* __restrict__ x,
                                                 const unsigned short* __restrict__ wfrag,
                                                 const float* __restrict__ dinv,
                                                 unsigned* __restrict__ z16) {
    __shared__ unsigned short wlds[32768];   // 64 KB: [h][fid=ct*4+kc][lane][8]
    const int t = threadIdx.x;
    {
        const uint4* src = (const uint4*)wfrag;
        uint4* dst = (uint4*)wlds;
#pragma unroll
        for (int j = 0; j < 8; ++j) dst[t + 512 * j] = src[t + 512 * j];
    }
    __syncthreads();

    const int wid = t >> 6, l = t & 63;      // wid 0..7
    const int lr = l & 15, lg = l >> 4;
    const unsigned short* wl_hi = wlds + l * 8;           // + fid*512
    const unsigned short* wl_lo = wlds + 16384 + l * 8;
    constexpr int NT2 = (N + 127) / 128;     // 782 tiles of 128 nodes

    for (int tile = blockIdx.x; tile < NT2; tile += gridDim.x) {
        const long node = (long)tile * 128 + wid * 16 + lr;
        const bool nv = node < N;
        const float* xr = x + node * C + lg * 8;

        // x row -> split-bf16 B-fragments, once per tile
        bf16x8 bh[4], bl[4];
#pragma unroll
        for (int kc = 0; kc < 4; ++kc) {
            float4 f0 = {0.f, 0.f, 0.f, 0.f}, f1 = {0.f, 0.f, 0.f, 0.f};
            if (nv) {
                f0 = *(const float4*)(xr + kc * 32);
                f1 = *(const float4*)(xr + kc * 32 + 4);
            }
#pragma unroll
            for (int e = 0; e < 8; ++e) {
                const float fe = (e < 4) ? (&f0.x)[e] : (&f1.x)[e - 4];
                const unsigned hb = f2bf(fe);
                bh[kc][e] = (short)hb;
                bl[kc][e] = (short)f2bf(fe - __uint_as_float(hb << 16));
            }
        }
        const float dv = nv ? dinv[node] : 0.f;

#pragma unroll
        for (int cp = 0; cp < 4; ++cp) {     // channel-tile pair (2cp, 2cp+1)
            f32x4 a0 = {0.f, 0.f, 0.f, 0.f}, a1 = {0.f, 0.f, 0.f, 0.f};
#pragma unroll
            for (int kc = 0; kc < 4; ++kc) {
                const int fo0 = ((2 * cp)     * 4 + kc) * 512;
                const int fo1 = ((2 * cp + 1) * 4 + kc) * 512;
                const bf16x8 h0 = *(const bf16x8*)(wl_hi + fo0);
                const bf16x8 o0 = *(const bf16x8*)(wl_lo + fo0);
                const bf16x8 h1 = *(const bf16x8*)(wl_hi + fo1);
                const bf16x8 o1 = *(const bf16x8*)(wl_lo + fo1);
                a0 = __builtin_amdgcn_mfma_f32_16x16x32_bf16(h0, bh[kc], a0, 0, 0, 0);
                a1 = __builtin_amdgcn_mfma_f32_16x16x32_bf16(h1, bh[kc], a1, 0, 0, 0);
                a0 = __builtin_amdgcn_mfma_f32_16x16x32_bf16(h0, bl[kc], a0, 0, 0, 0);
                a1 = __builtin_amdgcn_mfma_f32_16x16x32_bf16(h1, bl[kc], a1, 0, 0, 0);
                a0 = __builtin_amdgcn_mfma_f32_16x16x32_bf16(o0, bh[kc], a0, 0, 0, 0);
                a1 = __builtin_amdgcn_mfma_f32_16x16x32_bf16(o1, bh[kc], a1, 0, 0, 0);
            }
            if (nv) {
                uint2 p0 = {pack2(dv * a0[0], dv * a0[1]), pack2(dv * a0[2], dv * a0[3])};
                uint2 p1 = {pack2(dv * a1[0], dv * a1[1]), pack2(dv * a1[2], dv * a1[3])};
                *(uint2*)(z16 + node * 64 + (2 * cp)     * 8 + lg * 2) = p0;
                *(uint2*)(z16 + node * 64 + (2 * cp + 1) * 8 + lg * 2) = p1;
            }
        }
    }
}

// ---------------------------------------------------------------- gather ---
// One wave per node; lane owns channels 2*lane, 2*lane+1 (full 256 B rows).
// 3 node-range dispatches (profiling visibility). Two-bank pipeline,
// 16 row-loads in flight, scalar (readlane) addressing.
__global__ __launch_bounds__(256) void k_gather(const int* __restrict__ rowptr,
                                                const int* __restrict__ deg,
                                                const float* __restrict__ dinv,
                                                const int* __restrict__ adj,
                                                const unsigned* __restrict__ z16,
                                                const float* __restrict__ b,
                                                float* __restrict__ out,
                                                int u0, int u1) {
    const int u = u0 + blockIdx.x * 4 + (threadIdx.x >> 6);
    if (u >= u1) return;
    const int lane = threadIdx.x & 63;
    const int d  = __builtin_amdgcn_readfirstlane(deg[u]);
    const int pd = (d + 7) & ~7;
    const int st = __builtin_amdgcn_readfirstlane(rowptr[u]);
    const float du = dinv[u];

    const unsigned ms = z16[((size_t)(unsigned)u << 6) + lane];
    float ax = bf_lo(ms), ay = bf_hi(ms);

    unsigned q0, q1, q2, q3, q4, q5, q6, q7;
    unsigned r0, r1, r2, r3, r4, r5, r6, r7;

#define ZR(j) z16[((size_t)(unsigned)__builtin_amdgcn_readlane(v, (j)) << 6) + lane]
#define LD8(A, p) A##0 = ZR((p) + 0); A##1 = ZR((p) + 1); A##2 = ZR((p) + 2); \
                  A##3 = ZR((p) + 3); A##4 = ZR((p) + 4); A##5 = ZR((p) + 5); \
                  A##6 = ZR((p) + 6); A##7 = ZR((p) + 7);
#define AC8(A) ax += bf_lo(A##0); ay += bf_hi(A##0); ax += bf_lo(A##1); ay += bf_hi(A##1); \
               ax += bf_lo(A##2); ay += bf_hi(A##2); ax += bf_lo(A##3); ay += bf_hi(A##3); \
               ax += bf_lo(A##4); ay += bf_hi(A##4); ax += bf_lo(A##5); ay += bf_hi(A##5); \
               ax += bf_lo(A##6); ay += bf_hi(A##6); ax += bf_lo(A##7); ay += bf_hi(A##7);

    for (int j0 = 0; j0 < pd; j0 += 64) {
        const int cntc = min(64, pd - j0);   // multiple of 8, wave-uniform
        const int v = adj[st + j0 + lane];   // lanes >= cntc: slack reads, unused
        int p = 8;
        LD8(q, 0);
        for (; p + 16 <= cntc; p += 16) {
            LD8(r, p); AC8(q);
            LD8(q, p + 8); AC8(r);
        }
        if (p < cntc) { LD8(r, p); AC8(q); AC8(r); }
        else          { AC8(q); }
    }
#undef ZR
#undef LD8
#undef AC8

    const float2 bb = *(const float2*)(b + 2 * lane);
    float2 o = {fmaf(du, ax, bb.x), fmaf(du, ay, bb.y)};
    *(float2*)(out + (size_t)u * C + 2 * lane) = o;
}

// ---------------------------------------------------------------- launch ---
extern "C" void kernel_launch(void* const* d_in, const int* in_sizes, int n_in,
                              void* d_out, int out_size, void* d_ws, size_t ws_size,
                              hipStream_t stream) {
    const float* x  = (const float*)d_in[0];
    const float* W  = (const float*)d_in[1];
    const float* b  = (const float*)d_in[2];
    const int*   ei = (const int*)d_in[3];
    float* out = (float*)d_out;

    // workspace: z16 [(N+1)*64 u32 = 25.6 MB, overlays staging 14.8 MB] |
    //            adj [NBUCK*ADJ_STRIDE + 64 slack] | deg | dinv | rowptr |
    //            gcount [NBUCK*GPAD ints, line-padded] | wfrag [64 KB]
    char* p = (char*)d_ws;
    unsigned* z16 = (unsigned*)p;
    unsigned* staging = z16;                       // overlay (dead before gemm)
    p += (size_t)(N + 1) * 64 * sizeof(unsigned);
    int* adj = (int*)p;             p += ((size_t)NBUCK * ADJ_STRIDE + 64) * sizeof(int);
    int* deg = (int*)p;             p += (size_t)N * sizeof(int);
    float* dinv = (float*)p;        p += (size_t)N * sizeof(float);
    int* rowptr = (int*)p;          p += (size_t)(N + 4) * sizeof(int);
    int* gcount = (int*)p;          p += (size_t)NBUCK * GPAD * sizeof(int);
    unsigned short* wfrag = (unsigned short*)p;

    hipMemsetAsync(gcount, 0, (size_t)NBUCK * GPAD * sizeof(int), stream);
    k_bin<<<(E + 4095) / 4096, 256, 0, stream>>>(ei, gcount, staging, W, wfrag, z16);
    k_csr<<<NBUCK, 512, 0, stream>>>(staging, gcount, deg, dinv, rowptr, adj);
    k_gemm<<<256, 512, 0, stream>>>(x, wfrag, dinv, z16);
    const int third = (N + 2) / 3;
    for (int s = 0; s < 3; ++s) {
        const int u0 = s * third;
        const int u1 = (u0 + third < N) ? (u0 + third) : N;
        k_gather<<<(u1 - u0 + 3) / 4, 256, 0, stream>>>(rowptr, deg, dinv, adj, z16, b, out, u0, u1);
    }
}

// Round 9
// 330.924 us; speedup vs baseline: 1.1465x; 1.1465x over previous
//
#include <hip/hip_runtime.h>
#include <math.h>

constexpr int N = 100000;
constexpr int E = 1600000;
constexpr int C = 128;
constexpr int NPB   = 256;                       // nodes per bucket (pow2 -> shifts)
constexpr int NBUCK = (N + NPB - 1) / NPB;       // 391 buckets
constexpr int CAP   = 9472;                      // staging cap/bucket (mean 8192, +14 sigma)
constexpr int ADJ_STRIDE = CAP + NPB * 7;        // 11264: padded adj slots per bucket
constexpr int GPAD = 16;                         // gcount stride: 1 counter per 64B line

typedef __attribute__((ext_vector_type(8))) short bf16x8;
typedef __attribute__((ext_vector_type(4))) float f32x4;

__device__ inline unsigned f2bf(float f) {   // fp32 -> bf16 bits, RNE
    unsigned u = __float_as_uint(f);
    return (u + 0x7fffu + ((u >> 16) & 1u)) >> 16;
}
__device__ inline unsigned pack2(float lo, float hi) {
    return f2bf(lo) | (f2bf(hi) << 16);
}
__device__ inline float bf_lo(unsigned m) { return __uint_as_float(m << 16); }
__device__ inline float bf_hi(unsigned m) { return __uint_as_float(m & 0xffff0000u); }

// ------------------------------------------------------------- bin pass ----
// count -> reserve -> re-read+scatter; line-padded global counters (round-7
// fix, confirmed). Blocks 0..63 also split W into fragment-linear bf16
// hi/lo; block 0 zeroes dummy z-row N.
__global__ __launch_bounds__(256) void k_bin(const int* __restrict__ ei,
                                             int* __restrict__ gcount,
                                             unsigned* __restrict__ staging,
                                             const float* __restrict__ W,
                                             unsigned short* __restrict__ wfrag,
                                             unsigned* __restrict__ z16) {
    const int t = threadIdx.x;
    if (blockIdx.x < 64) {
        const int i = blockIdx.x * 256 + t;      // i < 16384 = C*C
        const int k = i >> 7, c = i & 127;
        const int ct = c >> 4, lr = c & 15;
        const int kc = k >> 5, lg = (k >> 3) & 3, e = k & 7;
        const int idx = ((ct * 4 + kc) * 64 + lg * 16 + lr) * 8 + e;
        const float f = W[i];
        const unsigned hb = f2bf(f);
        wfrag[idx]         = (unsigned short)hb;
        wfrag[16384 + idx] = (unsigned short)f2bf(f - __uint_as_float(hb << 16));
        if (blockIdx.x == 0 && t < 64) z16[(size_t)N * 64 + t] = 0u;
    }
    __shared__ int cnt[NBUCK];
    const long tile = (long)blockIdx.x * 4096;
    for (int i = t; i < NBUCK; i += 256) cnt[i] = 0;
    __syncthreads();
    // phase 1: count
#pragma unroll
    for (int j = 0; j < 16; ++j) {
        const long e = tile + j * 256 + t;
        if (e < E) {
            const int u = ei[e];
            const int v = ei[E + e];
            atomicAdd(&cnt[u >> 8], 1);
            atomicAdd(&cnt[v >> 8], 1);
        }
    }
    __syncthreads();
    // reserve: one padded global atomic per bucket; fold base into cnt
    for (int i = t; i < NBUCK; i += 256) {
        const int c = cnt[i];
        cnt[i] = atomicAdd(&gcount[i * GPAD], c);
    }
    __syncthreads();
    // phase 2: re-read (L2-warm) -> absolute position -> scatter
#pragma unroll
    for (int j = 0; j < 16; ++j) {
        const long e = tile + j * 256 + t;
        if (e < E) {
            const int u = ei[e];
            const int v = ei[E + e];
            const int bu = u >> 8, bv = v >> 8;
            const int pu = atomicAdd(&cnt[bu], 1);
            const int pv = atomicAdd(&cnt[bv], 1);
            staging[(size_t)bu * CAP + pu] = ((unsigned)(u & 255) << 17) | (unsigned)v;
            staging[(size_t)bv * CAP + pv] = ((unsigned)(v & 255) << 17) | (unsigned)u;
        }
    }
}

// -------------------------------------------------- per-bucket CSR build ---
__global__ __launch_bounds__(512) void k_csr(const unsigned* __restrict__ staging,
                                             const int* __restrict__ gcount,
                                             int* __restrict__ deg,
                                             float* __restrict__ dinv,
                                             int* __restrict__ rowptr,
                                             int* __restrict__ adj) {
    __shared__ int hist[NPB];
    __shared__ int wpart[4];
    const int g = blockIdx.x;
    const int t = threadIdx.x;
    const int lane = t & 63, wid = t >> 6;
    const int cnt = gcount[g * GPAD];
    int* slice = adj + (size_t)g * ADJ_STRIDE;
    for (int i = t; i < NPB; i += 512) hist[i] = 0;
    __syncthreads();
    const unsigned* base = staging + (size_t)g * CAP;
    for (int i = t; i < cnt; i += 512) atomicAdd(&hist[base[i] >> 17], 1);
    __syncthreads();
    const int d  = (t < NPB) ? hist[t] : 0;
    const int pd = (d + 7) & ~7;
    int v = pd;
#pragma unroll
    for (int off = 1; off < 64; off <<= 1) {
        int n = __shfl_up(v, off);
        if (lane >= off) v += n;
    }
    if (lane == 63 && wid < 4) wpart[wid] = v;
    __syncthreads();
    if (t == 0) {
        int r = 0;
#pragma unroll
        for (int w = 0; w < 4; ++w) { int x = wpart[w]; wpart[w] = r; r += x; }
    }
    __syncthreads();
    const int pstart = v - pd + ((wid < 4) ? wpart[wid] : 0);
    if (t < NPB) {
        const int node = g * NPB + t;
        if (node < N) {
            deg[node]    = d;
            dinv[node]   = rsqrtf((float)d + 1.0f);
            rowptr[node] = g * ADJ_STRIDE + pstart;
        }
        for (int i = d; i < pd; ++i) slice[pstart + i] = N;   // precise pad fill
    }
    __syncthreads();
    if (t < NPB) hist[t] = pstart;   // cursor for pass 2
    __syncthreads();
    for (int i = t; i < cnt; i += 512) {
        const unsigned e = base[i];
        const int pos = atomicAdd(&hist[e >> 17], 1);
        slice[pos] = (int)(e & 0x1ffffu);
    }
}

// ------------------------------------------------------------------ GEMM ---
// z16 = bf16(dinv * (x @ W)) via split-bf16 MFMA.
// Round-9: 512-thread blocks share the 64 KB W-LDS (2 blocks/CU = 16
// waves/CU possible), and the VGPR budget is earned STRUCTURALLY -- one
// f32x4 accumulator live at a time (single-ct loop), x pre-converted into
// bh/bl[4] (32 VGPR) -- NOT by a forced launch_bounds cap (round 8's
// __launch_bounds__(512,4) spilled ~250 MB to scratch: VGPR 64, FETCH
// 188 MB, WRITE 138 MB, 123-162 us). Plain __launch_bounds__(512).
__global__ __launch_bounds__(512) void k_gemm(const float* __restrict__ x,
                                              const unsigned short* __restrict__ wfrag,
                                              const float* __restrict__ dinv,
                                              unsigned* __restrict__ z16) {
    __shared__ unsigned short wlds[32768];   // 64 KB: [h][fid=ct*4+kc][lane][8]
    const int t = threadIdx.x;
    {
        const uint4* src = (const uint4*)wfrag;
        uint4* dst = (uint4*)wlds;
#pragma unroll
        for (int j = 0; j < 8; ++j) dst[t + 512 * j] = src[t + 512 * j];
    }
    __syncthreads();

    const int wid = t >> 6, l = t & 63;      // wid 0..7
    const int lr = l & 15, lg = l >> 4;
    const unsigned short* wl_hi = wlds + l * 8;           // + fid*512
    const unsigned short* wl_lo = wlds + 16384 + l * 8;
    constexpr int NT2 = (N + 127) / 128;     // 782 tiles of 128 nodes

    for (int tile = blockIdx.x; tile < NT2; tile += gridDim.x) {
        const long node = (long)tile * 128 + wid * 16 + lr;
        const bool nv = node < N;
        const float* xr = x + node * C + lg * 8;

        // x row -> split-bf16 B-fragments, once per tile (32 VGPR)
        bf16x8 bh[4], bl[4];
#pragma unroll
        for (int kc = 0; kc < 4; ++kc) {
            float4 f0 = {0.f, 0.f, 0.f, 0.f}, f1 = {0.f, 0.f, 0.f, 0.f};
            if (nv) {
                f0 = *(const float4*)(xr + kc * 32);
                f1 = *(const float4*)(xr + kc * 32 + 4);
            }
#pragma unroll
            for (int e = 0; e < 8; ++e) {
                const float fe = (e < 4) ? (&f0.x)[e] : (&f1.x)[e - 4];
                const unsigned hb = f2bf(fe);
                bh[kc][e] = (short)hb;
                bl[kc][e] = (short)f2bf(fe - __uint_as_float(hb << 16));
            }
        }
        const float dv = nv ? dinv[node] : 0.f;

#pragma unroll
        for (int ct = 0; ct < 8; ++ct) {     // one accumulator live at a time
            f32x4 a = {0.f, 0.f, 0.f, 0.f};
#pragma unroll
            for (int kc = 0; kc < 4; ++kc) {
                const int fo = (ct * 4 + kc) * 512;
                const bf16x8 h = *(const bf16x8*)(wl_hi + fo);
                const bf16x8 o = *(const bf16x8*)(wl_lo + fo);
                a = __builtin_amdgcn_mfma_f32_16x16x32_bf16(h, bh[kc], a, 0, 0, 0);
                a = __builtin_amdgcn_mfma_f32_16x16x32_bf16(h, bl[kc], a, 0, 0, 0);
                a = __builtin_amdgcn_mfma_f32_16x16x32_bf16(o, bh[kc], a, 0, 0, 0);
            }
            if (nv) {
                uint2 pk = {pack2(dv * a[0], dv * a[1]), pack2(dv * a[2], dv * a[3])};
                *(uint2*)(z16 + node * 64 + ct * 8 + lg * 2) = pk;
            }
        }
    }
}

// ---------------------------------------------------------------- gather ---
// One wave per node; lane owns channels 2*lane, 2*lane+1 (full 256 B rows).
// 3 node-range dispatches (profiling visibility). Two-bank pipeline,
// 16 row-loads in flight, scalar (readlane) addressing.
__global__ __launch_bounds__(256) void k_gather(const int* __restrict__ rowptr,
                                                const int* __restrict__ deg,
                                                const float* __restrict__ dinv,
                                                const int* __restrict__ adj,
                                                const unsigned* __restrict__ z16,
                                                const float* __restrict__ b,
                                                float* __restrict__ out,
                                                int u0, int u1) {
    const int u = u0 + blockIdx.x * 4 + (threadIdx.x >> 6);
    if (u >= u1) return;
    const int lane = threadIdx.x & 63;
    const int d  = __builtin_amdgcn_readfirstlane(deg[u]);
    const int pd = (d + 7) & ~7;
    const int st = __builtin_amdgcn_readfirstlane(rowptr[u]);
    const float du = dinv[u];

    const unsigned ms = z16[((size_t)(unsigned)u << 6) + lane];
    float ax = bf_lo(ms), ay = bf_hi(ms);

    unsigned q0, q1, q2, q3, q4, q5, q6, q7;
    unsigned r0, r1, r2, r3, r4, r5, r6, r7;

#define ZR(j) z16[((size_t)(unsigned)__builtin_amdgcn_readlane(v, (j)) << 6) + lane]
#define LD8(A, p) A##0 = ZR((p) + 0); A##1 = ZR((p) + 1); A##2 = ZR((p) + 2); \
                  A##3 = ZR((p) + 3); A##4 = ZR((p) + 4); A##5 = ZR((p) + 5); \
                  A##6 = ZR((p) + 6); A##7 = ZR((p) + 7);
#define AC8(A) ax += bf_lo(A##0); ay += bf_hi(A##0); ax += bf_lo(A##1); ay += bf_hi(A##1); \
               ax += bf_lo(A##2); ay += bf_hi(A##2); ax += bf_lo(A##3); ay += bf_hi(A##3); \
               ax += bf_lo(A##4); ay += bf_hi(A##4); ax += bf_lo(A##5); ay += bf_hi(A##5); \
               ax += bf_lo(A##6); ay += bf_hi(A##6); ax += bf_lo(A##7); ay += bf_hi(A##7);

    for (int j0 = 0; j0 < pd; j0 += 64) {
        const int cntc = min(64, pd - j0);   // multiple of 8, wave-uniform
        const int v = adj[st + j0 + lane];   // lanes >= cntc: slack reads, unused
        int p = 8;
        LD8(q, 0);
        for (; p + 16 <= cntc; p += 16) {
            LD8(r, p); AC8(q);
            LD8(q, p + 8); AC8(r);
        }
        if (p < cntc) { LD8(r, p); AC8(q); AC8(r); }
        else          { AC8(q); }
    }
#undef ZR
#undef LD8
#undef AC8

    const float2 bb = *(const float2*)(b + 2 * lane);
    float2 o = {fmaf(du, ax, bb.x), fmaf(du, ay, bb.y)};
    *(float2*)(out + (size_t)u * C + 2 * lane) = o;
}

// ---------------------------------------------------------------- launch ---
extern "C" void kernel_launch(void* const* d_in, const int* in_sizes, int n_in,
                              void* d_out, int out_size, void* d_ws, size_t ws_size,
                              hipStream_t stream) {
    const float* x  = (const float*)d_in[0];
    const float* W  = (const float*)d_in[1];
    const float* b  = (const float*)d_in[2];
    const int*   ei = (const int*)d_in[3];
    float* out = (float*)d_out;

    // workspace: z16 [(N+1)*64 u32 = 25.6 MB, overlays staging 14.8 MB] |
    //            adj [NBUCK*ADJ_STRIDE + 64 slack] | deg | dinv | rowptr |
    //            gcount [NBUCK*GPAD ints, line-padded] | wfrag [64 KB]
    char* p = (char*)d_ws;
    unsigned* z16 = (unsigned*)p;
    unsigned* staging = z16;                       // overlay (dead before gemm)
    p += (size_t)(N + 1) * 64 * sizeof(unsigned);
    int* adj = (int*)p;             p += ((size_t)NBUCK * ADJ_STRIDE + 64) * sizeof(int);
    int* deg = (int*)p;             p += (size_t)N * sizeof(int);
    float* dinv = (float*)p;        p += (size_t)N * sizeof(float);
    int* rowptr = (int*)p;          p += (size_t)(N + 4) * sizeof(int);
    int* gcount = (int*)p;          p += (size_t)NBUCK * GPAD * sizeof(int);
    unsigned short* wfrag = (unsigned short*)p;

    hipMemsetAsync(gcount, 0, (size_t)NBUCK * GPAD * sizeof(int), stream);
    k_bin<<<(E + 4095) / 4096, 256, 0, stream>>>(ei, gcount, staging, W, wfrag, z16);
    k_csr<<<NBUCK, 512, 0, stream>>>(staging, gcount, deg, dinv, rowptr, adj);
    k_gemm<<<512, 512, 0, stream>>>(x, wfrag, dinv, z16);
    const int third = (N + 2) / 3;
    for (int s = 0; s < 3; ++s) {
        const int u0 = s * third;
        const int u1 = (u0 + third < N) ? (u0 + third) : N;
        k_gather<<<(u1 - u0 + 3) / 4, 256, 0, stream>>>(rowptr, deg, dinv, adj, z16, b, out, u0, u1);
    }
}

// Round 10
// 298.990 us; speedup vs baseline: 1.2690x; 1.1068x over previous
//
#include <hip/hip_runtime.h>
#include <math.h>

constexpr int N = 100000;
constexpr int E = 1600000;
constexpr int C = 128;
constexpr int NPB   = 256;                       // nodes per bucket (pow2 -> shifts)
constexpr int NBUCK = (N + NPB - 1) / NPB;       // 391 buckets
constexpr int CAP   = 9472;                      // staging cap/bucket (mean 8192, +14 sigma)
constexpr int ADJ_STRIDE = CAP + NPB * 7;        // 11264: padded adj slots per bucket
constexpr int GPAD = 16;                         // gcount stride: 1 counter per 64B line

typedef __attribute__((ext_vector_type(8))) short bf16x8;
typedef __attribute__((ext_vector_type(4))) float f32x4;

__device__ inline unsigned f2bf(float f) {   // fp32 -> bf16 bits, RNE
    unsigned u = __float_as_uint(f);
    return (u + 0x7fffu + ((u >> 16) & 1u)) >> 16;
}
__device__ inline unsigned pack2(float lo, float hi) {
    return f2bf(lo) | (f2bf(hi) << 16);
}
__device__ inline float bf_lo(unsigned m) { return __uint_as_float(m << 16); }
__device__ inline float bf_hi(unsigned m) { return __uint_as_float(m & 0xffff0000u); }

// ------------------------------------------------------------- bin pass ----
// count -> reserve -> re-read+scatter; line-padded global counters (round-7
// fix, confirmed). Blocks 0..63 also split W into fragment-linear bf16
// hi/lo; block 0 zeroes dummy z-row N.
__global__ __launch_bounds__(256) void k_bin(const int* __restrict__ ei,
                                             int* __restrict__ gcount,
                                             unsigned* __restrict__ staging,
                                             const float* __restrict__ W,
                                             unsigned short* __restrict__ wfrag,
                                             unsigned* __restrict__ z16) {
    const int t = threadIdx.x;
    if (blockIdx.x < 64) {
        const int i = blockIdx.x * 256 + t;      // i < 16384 = C*C
        const int k = i >> 7, c = i & 127;
        const int ct = c >> 4, lr = c & 15;
        const int kc = k >> 5, lg = (k >> 3) & 3, e = k & 7;
        const int idx = ((ct * 4 + kc) * 64 + lg * 16 + lr) * 8 + e;
        const float f = W[i];
        const unsigned hb = f2bf(f);
        wfrag[idx]         = (unsigned short)hb;
        wfrag[16384 + idx] = (unsigned short)f2bf(f - __uint_as_float(hb << 16));
        if (blockIdx.x == 0 && t < 64) z16[(size_t)N * 64 + t] = 0u;
    }
    __shared__ int cnt[NBUCK];
    const long tile = (long)blockIdx.x * 4096;
    for (int i = t; i < NBUCK; i += 256) cnt[i] = 0;
    __syncthreads();
    // phase 1: count
#pragma unroll
    for (int j = 0; j < 16; ++j) {
        const long e = tile + j * 256 + t;
        if (e < E) {
            const int u = ei[e];
            const int v = ei[E + e];
            atomicAdd(&cnt[u >> 8], 1);
            atomicAdd(&cnt[v >> 8], 1);
        }
    }
    __syncthreads();
    // reserve: one padded global atomic per bucket; fold base into cnt
    for (int i = t; i < NBUCK; i += 256) {
        const int c = cnt[i];
        cnt[i] = atomicAdd(&gcount[i * GPAD], c);
    }
    __syncthreads();
    // phase 2: re-read (L2-warm) -> absolute position -> scatter
#pragma unroll
    for (int j = 0; j < 16; ++j) {
        const long e = tile + j * 256 + t;
        if (e < E) {
            const int u = ei[e];
            const int v = ei[E + e];
            const int bu = u >> 8, bv = v >> 8;
            const int pu = atomicAdd(&cnt[bu], 1);
            const int pv = atomicAdd(&cnt[bv], 1);
            staging[(size_t)bu * CAP + pu] = ((unsigned)(u & 255) << 17) | (unsigned)v;
            staging[(size_t)bv * CAP + pv] = ((unsigned)(v & 255) << 17) | (unsigned)u;
        }
    }
}

// -------------------------------------------------- per-bucket CSR build ---
__global__ __launch_bounds__(512) void k_csr(const unsigned* __restrict__ staging,
                                             const int* __restrict__ gcount,
                                             int* __restrict__ deg,
                                             float* __restrict__ dinv,
                                             int* __restrict__ rowptr,
                                             int* __restrict__ adj) {
    __shared__ int hist[NPB];
    __shared__ int wpart[4];
    const int g = blockIdx.x;
    const int t = threadIdx.x;
    const int lane = t & 63, wid = t >> 6;
    const int cnt = gcount[g * GPAD];
    int* slice = adj + (size_t)g * ADJ_STRIDE;
    for (int i = t; i < NPB; i += 512) hist[i] = 0;
    __syncthreads();
    const unsigned* base = staging + (size_t)g * CAP;
    for (int i = t; i < cnt; i += 512) atomicAdd(&hist[base[i] >> 17], 1);
    __syncthreads();
    const int d  = (t < NPB) ? hist[t] : 0;
    const int pd = (d + 7) & ~7;
    int v = pd;
#pragma unroll
    for (int off = 1; off < 64; off <<= 1) {
        int n = __shfl_up(v, off);
        if (lane >= off) v += n;
    }
    if (lane == 63 && wid < 4) wpart[wid] = v;
    __syncthreads();
    if (t == 0) {
        int r = 0;
#pragma unroll
        for (int w = 0; w < 4; ++w) { int x = wpart[w]; wpart[w] = r; r += x; }
    }
    __syncthreads();
    const int pstart = v - pd + ((wid < 4) ? wpart[wid] : 0);
    if (t < NPB) {
        const int node = g * NPB + t;
        if (node < N) {
            deg[node]    = d;
            dinv[node]   = rsqrtf((float)d + 1.0f);
            rowptr[node] = g * ADJ_STRIDE + pstart;
        }
        for (int i = d; i < pd; ++i) slice[pstart + i] = N;   // precise pad fill
    }
    __syncthreads();
    if (t < NPB) hist[t] = pstart;   // cursor for pass 2
    __syncthreads();
    for (int i = t; i < cnt; i += 512) {
        const unsigned e = base[i];
        const int pos = atomicAdd(&hist[e >> 17], 1);
        slice[pos] = (int)(e & 0x1ffffu);
    }
}

// ------------------------------------------------------------------ GEMM ---
// z16 = bf16(dinv * (x @ W)) via split-bf16 MFMA.
// Round-10: NO LDS, no barriers, no guards. N = 6250 groups x 16 nodes
// exactly; one group per wave. W fragments are read per-ct from global
// (fragment-linear wfrag; every wave walks the same 64 KB in the same
// order -> L1/L2-warm). Live set: bh/bl[4] (32 VGPR) + 2 fragments + 1
// accumulator -> ~80 VGPR, 5+ waves/SIMD with no launch_bounds cap and no
// LDS residency cliff. #pragma unroll 1 on the ct loop is the anti-hoist
// guard (r8/r9 lesson: the compiler pre-hoisting 64 W fragments into
// registers is what caused the 128-VGPR spills -> 150+ MB scratch traffic).
__global__ __launch_bounds__(256) void k_gemm(const float* __restrict__ x,
                                              const unsigned short* __restrict__ wfrag,
                                              const float* __restrict__ dinv,
                                              unsigned* __restrict__ z16) {
    const int g = blockIdx.x * 4 + (threadIdx.x >> 6);   // 16-node group id
    if (g >= N / 16) return;                             // N/16 = 6250 exact
    const int l  = threadIdx.x & 63;
    const int lr = l & 15, lg = l >> 4;
    const int node = g * 16 + lr;
    const float* xr = x + (size_t)node * C + lg * 8;

    // x row -> split-bf16 B-fragments (32 VGPR)
    bf16x8 bh[4], bl[4];
#pragma unroll
    for (int kc = 0; kc < 4; ++kc) {
        const float4 f0 = *(const float4*)(xr + kc * 32);
        const float4 f1 = *(const float4*)(xr + kc * 32 + 4);
#pragma unroll
        for (int e = 0; e < 8; ++e) {
            const float fe = (e < 4) ? (&f0.x)[e] : (&f1.x)[e - 4];
            const unsigned hb = f2bf(fe);
            bh[kc][e] = (short)hb;
            bl[kc][e] = (short)f2bf(fe - __uint_as_float(hb << 16));
        }
    }
    const float dv = dinv[node];
    const unsigned short* wl = wfrag + l * 8;

#pragma unroll 1
    for (int ct = 0; ct < 8; ++ct) {
        f32x4 a = {0.f, 0.f, 0.f, 0.f};
#pragma unroll
        for (int kc = 0; kc < 4; ++kc) {
            const int fo = (ct * 4 + kc) * 512;
            const bf16x8 h = *(const bf16x8*)(wl + fo);
            const bf16x8 o = *(const bf16x8*)(wl + 16384 + fo);
            a = __builtin_amdgcn_mfma_f32_16x16x32_bf16(h, bh[kc], a, 0, 0, 0);
            a = __builtin_amdgcn_mfma_f32_16x16x32_bf16(h, bl[kc], a, 0, 0, 0);
            a = __builtin_amdgcn_mfma_f32_16x16x32_bf16(o, bh[kc], a, 0, 0, 0);
        }
        uint2 pk = {pack2(dv * a[0], dv * a[1]), pack2(dv * a[2], dv * a[3])};
        *(uint2*)(z16 + (size_t)node * 64 + ct * 8 + lg * 2) = pk;
    }
}

// ---------------------------------------------------------------- gather ---
// One wave per node; lane owns channels 2*lane, 2*lane+1 (full 256 B rows).
// 3 node-range dispatches (profiling visibility). Two-bank pipeline,
// 16 row-loads in flight, scalar (readlane) addressing.
__global__ __launch_bounds__(256) void k_gather(const int* __restrict__ rowptr,
                                                const int* __restrict__ deg,
                                                const float* __restrict__ dinv,
                                                const int* __restrict__ adj,
                                                const unsigned* __restrict__ z16,
                                                const float* __restrict__ b,
                                                float* __restrict__ out,
                                                int u0, int u1) {
    const int u = u0 + blockIdx.x * 4 + (threadIdx.x >> 6);
    if (u >= u1) return;
    const int lane = threadIdx.x & 63;
    const int d  = __builtin_amdgcn_readfirstlane(deg[u]);
    const int pd = (d + 7) & ~7;
    const int st = __builtin_amdgcn_readfirstlane(rowptr[u]);
    const float du = dinv[u];

    const unsigned ms = z16[((size_t)(unsigned)u << 6) + lane];
    float ax = bf_lo(ms), ay = bf_hi(ms);

    unsigned q0, q1, q2, q3, q4, q5, q6, q7;
    unsigned r0, r1, r2, r3, r4, r5, r6, r7;

#define ZR(j) z16[((size_t)(unsigned)__builtin_amdgcn_readlane(v, (j)) << 6) + lane]
#define LD8(A, p) A##0 = ZR((p) + 0); A##1 = ZR((p) + 1); A##2 = ZR((p) + 2); \
                  A##3 = ZR((p) + 3); A##4 = ZR((p) + 4); A##5 = ZR((p) + 5); \
                  A##6 = ZR((p) + 6); A##7 = ZR((p) + 7);
#define AC8(A) ax += bf_lo(A##0); ay += bf_hi(A##0); ax += bf_lo(A##1); ay += bf_hi(A##1); \
               ax += bf_lo(A##2); ay += bf_hi(A##2); ax += bf_lo(A##3); ay += bf_hi(A##3); \
               ax += bf_lo(A##4); ay += bf_hi(A##4); ax += bf_lo(A##5); ay += bf_hi(A##5); \
               ax += bf_lo(A##6); ay += bf_hi(A##6); ax += bf_lo(A##7); ay += bf_hi(A##7);

    for (int j0 = 0; j0 < pd; j0 += 64) {
        const int cntc = min(64, pd - j0);   // multiple of 8, wave-uniform
        const int v = adj[st + j0 + lane];   // lanes >= cntc: slack reads, unused
        int p = 8;
        LD8(q, 0);
        for (; p + 16 <= cntc; p += 16) {
            LD8(r, p); AC8(q);
            LD8(q, p + 8); AC8(r);
        }
        if (p < cntc) { LD8(r, p); AC8(q); AC8(r); }
        else          { AC8(q); }
    }
#undef ZR
#undef LD8
#undef AC8

    const float2 bb = *(const float2*)(b + 2 * lane);
    float2 o = {fmaf(du, ax, bb.x), fmaf(du, ay, bb.y)};
    *(float2*)(out + (size_t)u * C + 2 * lane) = o;
}

// ---------------------------------------------------------------- launch ---
extern "C" void kernel_launch(void* const* d_in, const int* in_sizes, int n_in,
                              void* d_out, int out_size, void* d_ws, size_t ws_size,
                              hipStream_t stream) {
    const float* x  = (const float*)d_in[0];
    const float* W  = (const float*)d_in[1];
    const float* b  = (const float*)d_in[2];
    const int*   ei = (const int*)d_in[3];
    float* out = (float*)d_out;

    // workspace: z16 [(N+1)*64 u32 = 25.6 MB, overlays staging 14.8 MB] |
    //            adj [NBUCK*ADJ_STRIDE + 64 slack] | deg | dinv | rowptr |
    //            gcount [NBUCK*GPAD ints, line-padded] | wfrag [64 KB]
    char* p = (char*)d_ws;
    unsigned* z16 = (unsigned*)p;
    unsigned* staging = z16;                       // overlay (dead before gemm)
    p += (size_t)(N + 1) * 64 * sizeof(unsigned);
    int* adj = (int*)p;             p += ((size_t)NBUCK * ADJ_STRIDE + 64) * sizeof(int);
    int* deg = (int*)p;             p += (size_t)N * sizeof(int);
    float* dinv = (float*)p;        p += (size_t)N * sizeof(float);
    int* rowptr = (int*)p;          p += (size_t)(N + 4) * sizeof(int);
    int* gcount = (int*)p;          p += (size_t)NBUCK * GPAD * sizeof(int);
    unsigned short* wfrag = (unsigned short*)p;

    hipMemsetAsync(gcount, 0, (size_t)NBUCK * GPAD * sizeof(int), stream);
    k_bin<<<(E + 4095) / 4096, 256, 0, stream>>>(ei, gcount, staging, W, wfrag, z16);
    k_csr<<<NBUCK, 512, 0, stream>>>(staging, gcount, deg, dinv, rowptr, adj);
    k_gemm<<<(N / 16 + 3) / 4, 256, 0, stream>>>(x, wfrag, dinv, z16);
    const int third = (N + 2) / 3;
    for (int s = 0; s < 3; ++s) {
        const int u0 = s * third;
        const int u1 = (u0 + third < N) ? (u0 + third) : N;
        k_gather<<<(u1 - u0 + 3) / 4, 256, 0, stream>>>(rowptr, deg, dinv, adj, z16, b, out, u0, u1);
    }
}